// Round 3
// baseline (3599.696 us; speedup 1.0000x reference)
//
#include <hip/hip_runtime.h>
#include <math.h>

#define DD 512
#define TT 512

typedef __attribute__((ext_vector_type(8))) short short8;
typedef __attribute__((ext_vector_type(4))) float float4v;

static __device__ inline unsigned short f2bf(float f) {
    unsigned int b = __builtin_bit_cast(unsigned int, f);
    b += 0x7FFFu + ((b >> 16) & 1u);          // round-to-nearest-even
    return (unsigned short)(b >> 16);
}
static __device__ inline float bfhi(unsigned u) {   // high bf16 of a u32 pair
    return __builtin_bit_cast(float, u & 0xFFFF0000u);
}
static __device__ inline float bflo(unsigned u) {   // low bf16 of a u32 pair
    return __builtin_bit_cast(float, u << 16);
}

// ---------------------------------------------------------------------------
// Kernel A: fused projections (GEMM core identical to the verified R0
// version; epilogue identical to the twice-first-check-verified R2 version).
// Emits three separate bf16 operand arrays, each written by exactly one
// blockIdx.y (no cross-block sharing of any store granule):
//   PeB[page][tid*4+nt]  = bf16(X@We + be + bp)      page = ((t*4+b)*4+r)
//   Pl2[page][tid*4+nt]  = bf16(sigmoid(X@Wl + bl))
//   Pw2[page][tid*4+nt]  = bf16(sigmoid(X@Ww + bw))
// (b, qf-quarter, r) come from the batch row; tid = wv*64+qf*16+c0 is the
// rec_kernel thread owning cols {wv*64 + nt*16 + c0}.
// ---------------------------------------------------------------------------
__global__ __launch_bounds__(512) void proj_kernel(
    const float* __restrict__ X,
    const float* __restrict__ We, const float* __restrict__ be,
    const float* __restrict__ bp,
    const float* __restrict__ Wl, const float* __restrict__ bl,
    const float* __restrict__ Ww, const float* __restrict__ bw,
    unsigned short* __restrict__ PeB, unsigned short* __restrict__ Pl2,
    unsigned short* __restrict__ Pw2)
{
    __shared__ __align__(16) unsigned short Asw[8][64][8];
    __shared__ __align__(16) unsigned short Bsw[32][64][8];

    const int tid  = threadIdx.x;
    const int lane = tid & 63;
    const int wv   = tid >> 6;
    const int mat  = blockIdx.y;
    const int m0   = blockIdx.x * 128;

    const float* W = (mat == 0) ? We : (mat == 1 ? Wl : Ww);

    float4v acc[32];
#pragma unroll
    for (int i = 0; i < 32; i++) acc[i] = (float4v){0.f, 0.f, 0.f, 0.f};

    for (int kc = 0; kc < 16; kc++) {
        __syncthreads();
#pragma unroll
        for (int i = 0; i < 2; i++) {
            int f = tid + 512 * i;
            int m = f >> 3;
            int k = (f & 7) * 4;
            float4v xv = *reinterpret_cast<const float4v*>(
                &X[(m0 + m) * DD + kc * 32 + k]);
            int mt = m >> 4;
            int ln = (m & 15) | (((k >> 3) & 3) << 4);
            int j  = k & 7;
            Asw[mt][ln][j + 0] = f2bf(xv.x);
            Asw[mt][ln][j + 1] = f2bf(xv.y);
            Asw[mt][ln][j + 2] = f2bf(xv.z);
            Asw[mt][ln][j + 3] = f2bf(xv.w);
        }
#pragma unroll
        for (int i = 0; i < 8; i++) {
            int f = tid + 512 * i;
            int k = f >> 7;
            int n = (f & 127) * 4;
            float4v wv4 = *reinterpret_cast<const float4v*>(
                &W[(kc * 32 + k) * DD + n]);
            int q  = (k >> 3) & 3;
            int j  = k & 7;
            int nt = n >> 4;
            int lb = (n & 15) | (q << 4);
            Bsw[nt][lb + 0][j] = f2bf(wv4.x);
            Bsw[nt][lb + 1][j] = f2bf(wv4.y);
            Bsw[nt][lb + 2][j] = f2bf(wv4.z);
            Bsw[nt][lb + 3][j] = f2bf(wv4.w);
        }
        __syncthreads();
        short8 a = *reinterpret_cast<const short8*>(&Asw[wv][lane][0]);
#pragma unroll
        for (int nt = 0; nt < 32; nt++) {
            short8 b = *reinterpret_cast<const short8*>(&Bsw[nt][lane][0]);
            acc[nt] = __builtin_amdgcn_mfma_f32_16x16x32_bf16(a, b, acc[nt], 0, 0, 0);
        }
    }

    // ---- epilogue: operand-packed scatter ----
    const int q     = lane >> 4;
    const int c0    = lane & 15;
    const int tbase = m0 & 511;     // block covers one batch row, 128 t's
    const int rb    = m0 >> 9;      // batch row 0..63
    const int b     = rb >> 4;      // rec block
    const int qft   = (rb & 15) >> 2;
    const int rt    = rb & 3;

    unsigned short* P = (mat == 0) ? PeB : (mat == 1 ? Pl2 : Pw2);

#pragma unroll
    for (int wt = 0; wt < 8; wt++) {
        const int tidt = wt * 64 + qft * 16 + c0;
        float bs[4];
#pragma unroll
        for (int n2 = 0; n2 < 4; n2++) {
            const int col = (wt * 4 + n2) * 16 + c0;
            bs[n2] = (mat == 0) ? (be[col] + bp[col])
                                : ((mat == 1) ? bl[col] : bw[col]);
        }
#pragma unroll
        for (int r = 0; r < 4; r++) {
            const int t    = tbase + wv * 16 + q * 4 + r;
            const int page = (((t << 2) + b) << 2) + rt;
            float v[4];
#pragma unroll
            for (int n2 = 0; n2 < 4; n2++) {
                float x = acc[wt * 4 + n2][r] + bs[n2];
                v[n2] = (mat == 0) ? x : (1.0f / (1.0f + expf(-x)));
            }
            uint2 u;
            u.x = (unsigned)f2bf(v[0]) | ((unsigned)f2bf(v[1]) << 16);
            u.y = (unsigned)f2bf(v[2]) | ((unsigned)f2bf(v[3]) << 16);
            *reinterpret_cast<uint2*>(&P[(page << 11) + (tidt << 2)]) = u;
        }
    }
}

// ---------------------------------------------------------------------------
// Kernel B: persistent recurrence, no cross-workgroup traffic.
// 4 blocks x 512 threads; block blk owns batch rows 16*blk..16*blk+15 and all
// 512 columns (rows are independent recurrences, so the column split that
// forced global exchange in the 2023us baseline is gone entirely).
//
// Wp residency: wave wv owns cols [wv*64, wv*64+64): n-tiles 0..2 as MFMA
// B-fragments in VGPRs (192 regs/thread), n-tile 3 resident in LDS (128 KB).
// NOTE: NO min-waves clause in __launch_bounds__ — (512,2) would cap the
// allocator at 128 VGPR/thread (m69) and spill the 192-reg fragment file to
// scratch on the critical path (the R1/R2 3.1-3.5ms disaster).
//
// Belief circulates through a single-buffered 16 KB XOR-swizzled LDS A-panel:
// K-loop reads -> R-barrier -> epilogue writes -> W-barrier. Global operand
// loads are issued AFTER the R-barrier so no barrier's vmcnt(0) drain ever
// waits on a fresh HBM load. dout stores are in-step (round-0 pattern).
// ---------------------------------------------------------------------------
__global__ __launch_bounds__(512) void rec_kernel(
    const float* __restrict__ Wp,
    const unsigned short* __restrict__ PeB,
    const unsigned short* __restrict__ Pl2,
    const unsigned short* __restrict__ Pw2,
    float* __restrict__ dout)
{
    __shared__ __align__(16) unsigned short BswL[8][16][64][8]; // 128 KB
    __shared__ __align__(16) char AswP[16384];                  // 16 KB

    const int tid  = threadIdx.x;
    const int lane = tid & 63;
    const int wv   = tid >> 6;
    const int qf   = lane >> 4;
    const int c0   = lane & 15;
    const int blk  = blockIdx.x;     // 0..3

    short8 bf[3][16];                // B-fragments for n-tiles 0..2

    // ---- prologue: stage this wave's 64 Wp cols in 4 passes through its
    // private LDS slice; passes 0-2 -> registers, pass 3 stays resident.
#pragma unroll
    for (int nt = 0; nt < 4; nt++) {
        for (int it = 0; it < 32; it++) {
            const int f  = it * 64 + lane;
            const int k  = f >> 2;
            const int c4 = f & 3;
            const float4v w4 = *reinterpret_cast<const float4v*>(
                &Wp[(k << 9) + wv * 64 + nt * 16 + c4 * 4]);
            const int kk = k >> 5;
            const int qq = (k >> 3) & 3;
            const int j  = k & 7;
            const int lb = (c4 * 4) | (qq << 4);
            BswL[wv][kk][lb + 0][j] = f2bf(w4.x);
            BswL[wv][kk][lb + 1][j] = f2bf(w4.y);
            BswL[wv][kk][lb + 2][j] = f2bf(w4.z);
            BswL[wv][kk][lb + 3][j] = f2bf(w4.w);
        }
        if (nt < 3) {
#pragma unroll
            for (int kk = 0; kk < 16; kk++)
                bf[nt][kk] = *reinterpret_cast<const short8*>(&BswL[wv][kk][lane][0]);
        }
    }

    // belief(-1) = 0: zero the A-panel
#pragma unroll
    for (int i = 0; i < 8; i++)
        reinterpret_cast<unsigned*>(AswP)[tid + (i << 9)] = 0;
    __syncthreads();

    float pv[4][4];
#pragma unroll
    for (int nt = 0; nt < 4; nt++)
#pragma unroll
        for (int r = 0; r < 4; r++) pv[nt][r] = 0.0f;

    const int colb = wv * 64 + c0;           // + nt*16 at use
    const int aswz = (c0 & 7) << 4;          // A-panel XOR swizzle (row = c0)
    const int arp  = (c0 << 10) + (qf << 4); // row*1024 + qf*16
    const int bq   = (blk << 4) + (qf << 2); // batch row base

    for (int t = 0; t < TT; t++) {
        // K-loop: 16 kk x 4 MFMA; A from LDS panel, B from regs (+1 LDS nt)
        float4v acc[4];
#pragma unroll
        for (int i = 0; i < 4; i++) acc[i] = (float4v){0.f, 0.f, 0.f, 0.f};
#pragma unroll
        for (int kk = 0; kk < 16; kk++) {
            const short8 a = *reinterpret_cast<const short8*>(
                AswP + ((arp + (kk << 6)) ^ aswz));
            const short8 b3 = *reinterpret_cast<const short8*>(&BswL[wv][kk][lane][0]);
            acc[0] = __builtin_amdgcn_mfma_f32_16x16x32_bf16(a, bf[0][kk], acc[0], 0, 0, 0);
            acc[1] = __builtin_amdgcn_mfma_f32_16x16x32_bf16(a, bf[1][kk], acc[1], 0, 0, 0);
            acc[2] = __builtin_amdgcn_mfma_f32_16x16x32_bf16(a, bf[2][kk], acc[2], 0, 0, 0);
            acc[3] = __builtin_amdgcn_mfma_f32_16x16x32_bf16(a, b3,        acc[3], 0, 0, 0);
        }
        __syncthreads();                     // R: all A-panel reads done

        // operand loads (post-barrier: no barrier waits on these)
        const int pgb = ((t << 2) + blk) << 2;
        uint2 pe2[4], lk2[4], wr2[4];
#pragma unroll
        for (int r = 0; r < 4; r++) {
            const int off = ((pgb + r) << 11) + (tid << 2);
            pe2[r] = *reinterpret_cast<const uint2*>(&PeB[off]);
            lk2[r] = *reinterpret_cast<const uint2*>(&Pl2[off]);
            wr2[r] = *reinterpret_cast<const uint2*>(&Pw2[off]);
        }

        // epilogue: gates + tanh, update carry, dout store, A-panel for t+1
#pragma unroll
        for (int nt = 0; nt < 4; nt++) {
#pragma unroll
            for (int r = 0; r < 4; r++) {
                const unsigned pu = (nt < 2) ? pe2[r].x : pe2[r].y;
                const unsigned lu = (nt < 2) ? lk2[r].x : lk2[r].y;
                const unsigned wu = (nt < 2) ? wr2[r].x : wr2[r].y;
                const float pef = (nt & 1) ? bfhi(pu) : bflo(pu);
                const float lkf = (nt & 1) ? bfhi(lu) : bflo(lu);
                const float wrf = (nt & 1) ? bfhi(wu) : bflo(wu);
                const float pre  = acc[nt][r] + pef;          // pe incl. be+bp
                const float e    = __expf(2.0f * pre);
                const float cand = 1.0f - 2.0f / (e + 1.0f);  // tanh, inf-safe
                const float bel  = lkf * pv[nt][r] + wrf * cand;
                pv[nt][r] = bel;
                dout[((bq + r) << 18) + (t << 9) + colb + nt * 16] = bel;
                const int rl = (qf << 2) + r;
                const int wb = (((rl << 10) + ((colb + nt * 16) << 1))
                                ^ ((rl & 7) << 4));
                *reinterpret_cast<unsigned short*>(AswP + wb) = f2bf(bel);
            }
        }
        __syncthreads();                     // W: A-panel ready for t+1
    }
}

// ---------------------------------------------------------------------------
extern "C" void kernel_launch(void* const* d_in, const int* in_sizes, int n_in,
                              void* d_out, int out_size, void* d_ws, size_t ws_size,
                              hipStream_t stream) {
    (void)in_sizes; (void)n_in; (void)out_size; (void)ws_size;
    const float* X  = (const float*)d_in[0];
    const float* We = (const float*)d_in[1];
    const float* be = (const float*)d_in[2];
    const float* Wp = (const float*)d_in[3];
    const float* bp = (const float*)d_in[4];
    const float* Wl = (const float*)d_in[5];
    const float* bl = (const float*)d_in[6];
    const float* Ww = (const float*)d_in[7];
    const float* bw = (const float*)d_in[8];
    float* out = (float*)d_out;

    char* ws = (char*)d_ws;
    unsigned short* PeB = (unsigned short*)ws;                   // 32 MB
    unsigned short* Pl2 = (unsigned short*)(ws + 33554432);      // 32 MB
    unsigned short* Pw2 = (unsigned short*)(ws + 67108864);      // 32 MB

    proj_kernel<<<dim3(256, 3), 512, 0, stream>>>(X, We, be, bp, Wl, bl,
                                                  Ww, bw, PeB, Pl2, Pw2);
    rec_kernel<<<dim3(4), 512, 0, stream>>>(Wp, PeB, Pl2, Pw2, out);
}

// Round 4
// 3361.777 us; speedup vs baseline: 1.0708x; 1.0708x over previous
//
#include <hip/hip_runtime.h>
#include <math.h>

#define DD 512
#define TT 512

typedef __attribute__((ext_vector_type(8))) short short8;
typedef __attribute__((ext_vector_type(4))) float float4v;

static __device__ inline unsigned short f2bf(float f) {
    unsigned int b = __builtin_bit_cast(unsigned int, f);
    b += 0x7FFFu + ((b >> 16) & 1u);          // round-to-nearest-even
    return (unsigned short)(b >> 16);
}
static __device__ inline float bfhi(unsigned u) {   // high bf16 of a u32 pair
    return __builtin_bit_cast(float, u & 0xFFFF0000u);
}
static __device__ inline float bflo(unsigned u) {   // low bf16 of a u32 pair
    return __builtin_bit_cast(float, u << 16);
}

// ---------------------------------------------------------------------------
// Kernel A: fused projections — byte-identical to the R3-verified version.
//   PeB[page][tid*4+nt]  = bf16(X@We + be + bp)      page = ((t*4+b)*4+r)
//   Pl2[page][tid*4+nt]  = bf16(sigmoid(X@Wl + bl))
//   Pw2[page][tid*4+nt]  = bf16(sigmoid(X@Ww + bw))
// (b, qf-quarter, r) come from the batch row; tid = wv*64+qf*16+c0 is the
// rec_kernel thread owning cols {wv*64 + nt*16 + c0}.
// ---------------------------------------------------------------------------
__global__ __launch_bounds__(512) void proj_kernel(
    const float* __restrict__ X,
    const float* __restrict__ We, const float* __restrict__ be,
    const float* __restrict__ bp,
    const float* __restrict__ Wl, const float* __restrict__ bl,
    const float* __restrict__ Ww, const float* __restrict__ bw,
    unsigned short* __restrict__ PeB, unsigned short* __restrict__ Pl2,
    unsigned short* __restrict__ Pw2)
{
    __shared__ __align__(16) unsigned short Asw[8][64][8];
    __shared__ __align__(16) unsigned short Bsw[32][64][8];

    const int tid  = threadIdx.x;
    const int lane = tid & 63;
    const int wv   = tid >> 6;
    const int mat  = blockIdx.y;
    const int m0   = blockIdx.x * 128;

    const float* W = (mat == 0) ? We : (mat == 1 ? Wl : Ww);

    float4v acc[32];
#pragma unroll
    for (int i = 0; i < 32; i++) acc[i] = (float4v){0.f, 0.f, 0.f, 0.f};

    for (int kc = 0; kc < 16; kc++) {
        __syncthreads();
#pragma unroll
        for (int i = 0; i < 2; i++) {
            int f = tid + 512 * i;
            int m = f >> 3;
            int k = (f & 7) * 4;
            float4v xv = *reinterpret_cast<const float4v*>(
                &X[(m0 + m) * DD + kc * 32 + k]);
            int mt = m >> 4;
            int ln = (m & 15) | (((k >> 3) & 3) << 4);
            int j  = k & 7;
            Asw[mt][ln][j + 0] = f2bf(xv.x);
            Asw[mt][ln][j + 1] = f2bf(xv.y);
            Asw[mt][ln][j + 2] = f2bf(xv.z);
            Asw[mt][ln][j + 3] = f2bf(xv.w);
        }
#pragma unroll
        for (int i = 0; i < 8; i++) {
            int f = tid + 512 * i;
            int k = f >> 7;
            int n = (f & 127) * 4;
            float4v wv4 = *reinterpret_cast<const float4v*>(
                &W[(kc * 32 + k) * DD + n]);
            int q  = (k >> 3) & 3;
            int j  = k & 7;
            int nt = n >> 4;
            int lb = (n & 15) | (q << 4);
            Bsw[nt][lb + 0][j] = f2bf(wv4.x);
            Bsw[nt][lb + 1][j] = f2bf(wv4.y);
            Bsw[nt][lb + 2][j] = f2bf(wv4.z);
            Bsw[nt][lb + 3][j] = f2bf(wv4.w);
        }
        __syncthreads();
        short8 a = *reinterpret_cast<const short8*>(&Asw[wv][lane][0]);
#pragma unroll
        for (int nt = 0; nt < 32; nt++) {
            short8 b = *reinterpret_cast<const short8*>(&Bsw[nt][lane][0]);
            acc[nt] = __builtin_amdgcn_mfma_f32_16x16x32_bf16(a, b, acc[nt], 0, 0, 0);
        }
    }

    // ---- epilogue: operand-packed scatter ----
    const int q     = lane >> 4;
    const int c0    = lane & 15;
    const int tbase = m0 & 511;     // block covers one batch row, 128 t's
    const int rb    = m0 >> 9;      // batch row 0..63
    const int b     = rb >> 4;      // rec block
    const int qft   = (rb & 15) >> 2;
    const int rt    = rb & 3;

    unsigned short* P = (mat == 0) ? PeB : (mat == 1 ? Pl2 : Pw2);

#pragma unroll
    for (int wt = 0; wt < 8; wt++) {
        const int tidt = wt * 64 + qft * 16 + c0;
        float bs[4];
#pragma unroll
        for (int n2 = 0; n2 < 4; n2++) {
            const int col = (wt * 4 + n2) * 16 + c0;
            bs[n2] = (mat == 0) ? (be[col] + bp[col])
                                : ((mat == 1) ? bl[col] : bw[col]);
        }
#pragma unroll
        for (int r = 0; r < 4; r++) {
            const int t    = tbase + wv * 16 + q * 4 + r;
            const int page = (((t << 2) + b) << 2) + rt;
            float v[4];
#pragma unroll
            for (int n2 = 0; n2 < 4; n2++) {
                float x = acc[wt * 4 + n2][r] + bs[n2];
                v[n2] = (mat == 0) ? x : (1.0f / (1.0f + expf(-x)));
            }
            uint2 u;
            u.x = (unsigned)f2bf(v[0]) | ((unsigned)f2bf(v[1]) << 16);
            u.y = (unsigned)f2bf(v[2]) | ((unsigned)f2bf(v[3]) << 16);
            *reinterpret_cast<uint2*>(&P[(page << 11) + (tidt << 2)]) = u;
        }
    }
}

// ---------------------------------------------------------------------------
// Kernel B: persistent recurrence (R3 structure, two changes):
//  1. amdgpu_waves_per_eu(2,2): exactly 2 waves/EU -> 256-reg unified budget.
//     R3's allocator targeted 128 VGPRs (measured) and spilled the 192-reg
//     Wp fragment file to scratch — the entire 3.2ms.
//  2. Operand loads issued BEFORE the K-loop: latency hides under 64 MFMAs
//     and the R-barrier's mandatory vmcnt(0) drain. Peak live regs:
//     bf 192 + acc 16 + pv 16 + operands 24 + temps ~8 = ~248 <= 256.
// Everything else (A-panel swizzle, barrier protocol, dout stores, operand
// layout) is byte-identical to the R3-verified kernel.
// ---------------------------------------------------------------------------
__global__ __attribute__((amdgpu_waves_per_eu(2, 2))) __launch_bounds__(512)
void rec_kernel(
    const float* __restrict__ Wp,
    const unsigned short* __restrict__ PeB,
    const unsigned short* __restrict__ Pl2,
    const unsigned short* __restrict__ Pw2,
    float* __restrict__ dout)
{
    __shared__ __align__(16) unsigned short BswL[8][16][64][8]; // 128 KB
    __shared__ __align__(16) char AswP[16384];                  // 16 KB

    const int tid  = threadIdx.x;
    const int lane = tid & 63;
    const int wv   = tid >> 6;
    const int qf   = lane >> 4;
    const int c0   = lane & 15;
    const int blk  = blockIdx.x;     // 0..3

    short8 bf[3][16];                // B-fragments for n-tiles 0..2

    // ---- prologue: stage this wave's 64 Wp cols in 4 passes through its
    // private LDS slice; passes 0-2 -> registers, pass 3 stays resident.
#pragma unroll
    for (int nt = 0; nt < 4; nt++) {
        for (int it = 0; it < 32; it++) {
            const int f  = it * 64 + lane;
            const int k  = f >> 2;
            const int c4 = f & 3;
            const float4v w4 = *reinterpret_cast<const float4v*>(
                &Wp[(k << 9) + wv * 64 + nt * 16 + c4 * 4]);
            const int kk = k >> 5;
            const int qq = (k >> 3) & 3;
            const int j  = k & 7;
            const int lb = (c4 * 4) | (qq << 4);
            BswL[wv][kk][lb + 0][j] = f2bf(w4.x);
            BswL[wv][kk][lb + 1][j] = f2bf(w4.y);
            BswL[wv][kk][lb + 2][j] = f2bf(w4.z);
            BswL[wv][kk][lb + 3][j] = f2bf(w4.w);
        }
        if (nt < 3) {
#pragma unroll
            for (int kk = 0; kk < 16; kk++)
                bf[nt][kk] = *reinterpret_cast<const short8*>(&BswL[wv][kk][lane][0]);
        }
    }

    // belief(-1) = 0: zero the A-panel
#pragma unroll
    for (int i = 0; i < 8; i++)
        reinterpret_cast<unsigned*>(AswP)[tid + (i << 9)] = 0;
    __syncthreads();

    float pv[4][4];
#pragma unroll
    for (int nt = 0; nt < 4; nt++)
#pragma unroll
        for (int r = 0; r < 4; r++) pv[nt][r] = 0.0f;

    const int colb = wv * 64 + c0;           // + nt*16 at use
    const int aswz = (c0 & 7) << 4;          // A-panel XOR swizzle (row = c0)
    const int arp  = (c0 << 10) + (qf << 4); // row*1024 + qf*16
    const int bq   = (blk << 4) + (qf << 2); // batch row base

    for (int t = 0; t < TT; t++) {
        // operand loads for THIS step, issued pre-K-loop: latency hides
        // under the MFMAs; the R-barrier's vmcnt(0) drain completes them.
        const int pgb = ((t << 2) + blk) << 2;
        uint2 pe2[4], lk2[4], wr2[4];
#pragma unroll
        for (int r = 0; r < 4; r++) {
            const int off = ((pgb + r) << 11) + (tid << 2);
            pe2[r] = *reinterpret_cast<const uint2*>(&PeB[off]);
            lk2[r] = *reinterpret_cast<const uint2*>(&Pl2[off]);
            wr2[r] = *reinterpret_cast<const uint2*>(&Pw2[off]);
        }

        // K-loop: 16 kk x 4 MFMA; A from LDS panel, B from regs (+1 LDS nt)
        float4v acc[4];
#pragma unroll
        for (int i = 0; i < 4; i++) acc[i] = (float4v){0.f, 0.f, 0.f, 0.f};
#pragma unroll
        for (int kk = 0; kk < 16; kk++) {
            const short8 a = *reinterpret_cast<const short8*>(
                AswP + ((arp + (kk << 6)) ^ aswz));
            const short8 b3 = *reinterpret_cast<const short8*>(&BswL[wv][kk][lane][0]);
            acc[0] = __builtin_amdgcn_mfma_f32_16x16x32_bf16(a, bf[0][kk], acc[0], 0, 0, 0);
            acc[1] = __builtin_amdgcn_mfma_f32_16x16x32_bf16(a, bf[1][kk], acc[1], 0, 0, 0);
            acc[2] = __builtin_amdgcn_mfma_f32_16x16x32_bf16(a, bf[2][kk], acc[2], 0, 0, 0);
            acc[3] = __builtin_amdgcn_mfma_f32_16x16x32_bf16(a, b3,        acc[3], 0, 0, 0);
        }
        __syncthreads();                     // R: all A-panel reads done

        // epilogue: gates + tanh, update carry, dout store, A-panel for t+1
#pragma unroll
        for (int nt = 0; nt < 4; nt++) {
#pragma unroll
            for (int r = 0; r < 4; r++) {
                const unsigned pu = (nt < 2) ? pe2[r].x : pe2[r].y;
                const unsigned lu = (nt < 2) ? lk2[r].x : lk2[r].y;
                const unsigned wu = (nt < 2) ? wr2[r].x : wr2[r].y;
                const float pef = (nt & 1) ? bfhi(pu) : bflo(pu);
                const float lkf = (nt & 1) ? bfhi(lu) : bflo(lu);
                const float wrf = (nt & 1) ? bfhi(wu) : bflo(wu);
                const float pre  = acc[nt][r] + pef;          // pe incl. be+bp
                const float e    = __expf(2.0f * pre);
                const float cand = 1.0f - 2.0f / (e + 1.0f);  // tanh, inf-safe
                const float bel  = lkf * pv[nt][r] + wrf * cand;
                pv[nt][r] = bel;
                dout[((bq + r) << 18) + (t << 9) + colb + nt * 16] = bel;
                const int rl = (qf << 2) + r;
                const int wb = (((rl << 10) + ((colb + nt * 16) << 1))
                                ^ ((rl & 7) << 4));
                *reinterpret_cast<unsigned short*>(AswP + wb) = f2bf(bel);
            }
        }
        __syncthreads();                     // W: A-panel ready for t+1
    }
}

// ---------------------------------------------------------------------------
extern "C" void kernel_launch(void* const* d_in, const int* in_sizes, int n_in,
                              void* d_out, int out_size, void* d_ws, size_t ws_size,
                              hipStream_t stream) {
    (void)in_sizes; (void)n_in; (void)out_size; (void)ws_size;
    const float* X  = (const float*)d_in[0];
    const float* We = (const float*)d_in[1];
    const float* be = (const float*)d_in[2];
    const float* Wp = (const float*)d_in[3];
    const float* bp = (const float*)d_in[4];
    const float* Wl = (const float*)d_in[5];
    const float* bl = (const float*)d_in[6];
    const float* Ww = (const float*)d_in[7];
    const float* bw = (const float*)d_in[8];
    float* out = (float*)d_out;

    char* ws = (char*)d_ws;
    unsigned short* PeB = (unsigned short*)ws;                   // 32 MB
    unsigned short* Pl2 = (unsigned short*)(ws + 33554432);      // 32 MB
    unsigned short* Pw2 = (unsigned short*)(ws + 67108864);      // 32 MB

    proj_kernel<<<dim3(256, 3), 512, 0, stream>>>(X, We, be, bp, Wl, bl,
                                                  Ww, bw, PeB, Pl2, Pw2);
    rec_kernel<<<dim3(4), 512, 0, stream>>>(Wp, PeB, Pl2, Pw2, out);
}

// Round 6
// 3110.006 us; speedup vs baseline: 1.1575x; 1.0810x over previous
//
#include <hip/hip_runtime.h>
#include <math.h>

#define DD 512
#define TT 512

typedef __attribute__((ext_vector_type(8))) short short8;
typedef __attribute__((ext_vector_type(4))) float float4v;

static __device__ inline unsigned short f2bf(float f) {
    unsigned int b = __builtin_bit_cast(unsigned int, f);
    b += 0x7FFFu + ((b >> 16) & 1u);          // round-to-nearest-even
    return (unsigned short)(b >> 16);
}
static __device__ inline float bfhi(unsigned u) {   // high bf16 of a u32 pair
    return __builtin_bit_cast(float, u & 0xFFFF0000u);
}
static __device__ inline float bflo(unsigned u) {   // low bf16 of a u32 pair
    return __builtin_bit_cast(float, u << 16);
}

// ---------------------------------------------------------------------------
// Kernel P: one-shot prep — repack Wp's nt=3 columns of each wave slice into
// MFMA-fragment order so rec_kernel can stream them as single dwordx4 loads:
//   Wq[((kk*8 + wv)*64 + lane)*8 + j] = bf16(Wp[kk*32 + (lane>>4)*8 + j]
//                                             [wv*64 + 48 + (lane&15)])
// Size: 16*8*64*16 B = 128 KB. L2-resident thereafter.
// ---------------------------------------------------------------------------
__global__ __launch_bounds__(64) void prep_kernel(
    const float* __restrict__ Wp, unsigned short* __restrict__ Wq)
{
    const int lane = threadIdx.x;      // 0..63
    const int g    = blockIdx.x;       // 0..127 = kk*8 + wv
    const int kk   = g >> 3;
    const int wv   = g & 7;
    const int col  = wv * 64 + 48 + (lane & 15);
    const int k0   = kk * 32 + (lane >> 4) * 8;
    unsigned short v[8];
#pragma unroll
    for (int j = 0; j < 8; j++) v[j] = f2bf(Wp[(k0 + j) * DD + col]);
    uint4 u;
    u.x = (unsigned)v[0] | ((unsigned)v[1] << 16);
    u.y = (unsigned)v[2] | ((unsigned)v[3] << 16);
    u.z = (unsigned)v[4] | ((unsigned)v[5] << 16);
    u.w = (unsigned)v[6] | ((unsigned)v[7] << 16);
    *reinterpret_cast<uint4*>(&Wq[(g * 64 + lane) * 8]) = u;
}

// ---------------------------------------------------------------------------
// Kernel A: fused projections — byte-identical to the R3/R4-verified version.
//   PeB[page][tid*4+nt]  = bf16(X@We + be + bp)      page = ((t*4+b)*4+r)
//   Pl2[page][tid*4+nt]  = bf16(sigmoid(X@Wl + bl))
//   Pw2[page][tid*4+nt]  = bf16(sigmoid(X@Ww + bw))
// ---------------------------------------------------------------------------
__global__ __launch_bounds__(512) void proj_kernel(
    const float* __restrict__ X,
    const float* __restrict__ We, const float* __restrict__ be,
    const float* __restrict__ bp,
    const float* __restrict__ Wl, const float* __restrict__ bl,
    const float* __restrict__ Ww, const float* __restrict__ bw,
    unsigned short* __restrict__ PeB, unsigned short* __restrict__ Pl2,
    unsigned short* __restrict__ Pw2)
{
    __shared__ __align__(16) unsigned short Asw[8][64][8];
    __shared__ __align__(16) unsigned short Bsw[32][64][8];

    const int tid  = threadIdx.x;
    const int lane = tid & 63;
    const int wv   = tid >> 6;
    const int mat  = blockIdx.y;
    const int m0   = blockIdx.x * 128;

    const float* W = (mat == 0) ? We : (mat == 1 ? Wl : Ww);

    float4v acc[32];
#pragma unroll
    for (int i = 0; i < 32; i++) acc[i] = (float4v){0.f, 0.f, 0.f, 0.f};

    for (int kc = 0; kc < 16; kc++) {
        __syncthreads();
#pragma unroll
        for (int i = 0; i < 2; i++) {
            int f = tid + 512 * i;
            int m = f >> 3;
            int k = (f & 7) * 4;
            float4v xv = *reinterpret_cast<const float4v*>(
                &X[(m0 + m) * DD + kc * 32 + k]);
            int mt = m >> 4;
            int ln = (m & 15) | (((k >> 3) & 3) << 4);
            int j  = k & 7;
            Asw[mt][ln][j + 0] = f2bf(xv.x);
            Asw[mt][ln][j + 1] = f2bf(xv.y);
            Asw[mt][ln][j + 2] = f2bf(xv.z);
            Asw[mt][ln][j + 3] = f2bf(xv.w);
        }
#pragma unroll
        for (int i = 0; i < 8; i++) {
            int f = tid + 512 * i;
            int k = f >> 7;
            int n = (f & 127) * 4;
            float4v wv4 = *reinterpret_cast<const float4v*>(
                &W[(kc * 32 + k) * DD + n]);
            int q  = (k >> 3) & 3;
            int j  = k & 7;
            int nt = n >> 4;
            int lb = (n & 15) | (q << 4);
            Bsw[nt][lb + 0][j] = f2bf(wv4.x);
            Bsw[nt][lb + 1][j] = f2bf(wv4.y);
            Bsw[nt][lb + 2][j] = f2bf(wv4.z);
            Bsw[nt][lb + 3][j] = f2bf(wv4.w);
        }
        __syncthreads();
        short8 a = *reinterpret_cast<const short8*>(&Asw[wv][lane][0]);
#pragma unroll
        for (int nt = 0; nt < 32; nt++) {
            short8 b = *reinterpret_cast<const short8*>(&Bsw[nt][lane][0]);
            acc[nt] = __builtin_amdgcn_mfma_f32_16x16x32_bf16(a, b, acc[nt], 0, 0, 0);
        }
    }

    // ---- epilogue: operand-packed scatter ----
    const int q     = lane >> 4;
    const int c0    = lane & 15;
    const int tbase = m0 & 511;     // block covers one batch row, 128 t's
    const int rb    = m0 >> 9;      // batch row 0..63
    const int b     = rb >> 4;      // rec block
    const int qft   = (rb & 15) >> 2;
    const int rt    = rb & 3;

    unsigned short* P = (mat == 0) ? PeB : (mat == 1 ? Pl2 : Pw2);

#pragma unroll
    for (int wt = 0; wt < 8; wt++) {
        const int tidt = wt * 64 + qft * 16 + c0;
        float bs[4];
#pragma unroll
        for (int n2 = 0; n2 < 4; n2++) {
            const int col = (wt * 4 + n2) * 16 + c0;
            bs[n2] = (mat == 0) ? (be[col] + bp[col])
                                : ((mat == 1) ? bl[col] : bw[col]);
        }
#pragma unroll
        for (int r = 0; r < 4; r++) {
            const int t    = tbase + wv * 16 + q * 4 + r;
            const int page = (((t << 2) + b) << 2) + rt;
            float v[4];
#pragma unroll
            for (int n2 = 0; n2 < 4; n2++) {
                float x = acc[wt * 4 + n2][r] + bs[n2];
                v[n2] = (mat == 0) ? x : (1.0f / (1.0f + expf(-x)));
            }
            uint2 u;
            u.x = (unsigned)f2bf(v[0]) | ((unsigned)f2bf(v[1]) << 16);
            u.y = (unsigned)f2bf(v[2]) | ((unsigned)f2bf(v[3]) << 16);
            *reinterpret_cast<uint2*>(&P[(page << 11) + (tidt << 2)]) = u;
        }
    }
}

// ---------------------------------------------------------------------------
// Kernel B: persistent recurrence. 4 blocks x 512 threads; block blk owns
// batch rows 16*blk..+15 and all 512 cols (no cross-workgroup exchange).
// Wp residency per wave (64 cols = 4 n-tiles), slack-first split:
//   nt 0,1 -> VGPR fragments (128 regs)
//   nt 2   -> LDS (8 waves x 16 KB = 128 KB, conflict-free layout)
//   nt 3   -> streamed per-step from Wq (128 KB, L2-resident on this
//             block's private XCD L2; 3-deep rotating prefetch)
// Peak live ~200 regs incl. acc — fits the 2-waves/EU 256-reg budget with
// real slack (R3/R4's 192-frag design had zero slack and spilled).
// Belief circulates via single-buffered 16 KB XOR-swizzled A-panel,
// 2 barriers/step. Operand loads post-R-barrier (epilogue-only liveness).
// ---------------------------------------------------------------------------
__global__ __attribute__((amdgpu_flat_work_group_size(512, 512),
                          amdgpu_waves_per_eu(2, 2)))
void rec_kernel(
    const float* __restrict__ Wp,
    const unsigned short* __restrict__ Wq,
    const unsigned short* __restrict__ PeB,
    const unsigned short* __restrict__ Pl2,
    const unsigned short* __restrict__ Pw2,
    float* __restrict__ dout)
{
    __shared__ __align__(16) unsigned short BswL[8][16][64][8]; // 128 KB
    __shared__ __align__(16) char AswP[16384];                  // 16 KB

    const int tid  = threadIdx.x;
    const int lane = tid & 63;
    const int wv   = tid >> 6;
    const int qf   = lane >> 4;
    const int c0   = lane & 15;
    const int blk  = blockIdx.x;     // 0..3

    short8 bf[2][16];                // B-fragments for n-tiles 0,1 (128 regs)

    // ---- prologue: stage nt 0..2 through this wave's private LDS slice;
    // nt 0,1 -> registers, nt 2 stays resident in LDS.
#pragma unroll
    for (int nt = 0; nt < 3; nt++) {
        for (int it = 0; it < 32; it++) {
            const int f  = it * 64 + lane;
            const int k  = f >> 2;
            const int c4 = f & 3;
            const float4v w4 = *reinterpret_cast<const float4v*>(
                &Wp[(k << 9) + wv * 64 + nt * 16 + c4 * 4]);
            const int kk = k >> 5;
            const int qq = (k >> 3) & 3;
            const int j  = k & 7;
            const int lb = (c4 * 4) | (qq << 4);
            BswL[wv][kk][lb + 0][j] = f2bf(w4.x);
            BswL[wv][kk][lb + 1][j] = f2bf(w4.y);
            BswL[wv][kk][lb + 2][j] = f2bf(w4.z);
            BswL[wv][kk][lb + 3][j] = f2bf(w4.w);
        }
        if (nt < 2) {
#pragma unroll
            for (int kk = 0; kk < 16; kk++)
                bf[nt][kk] = *reinterpret_cast<const short8*>(&BswL[wv][kk][lane][0]);
        }
    }

    // belief(-1) = 0: zero the A-panel
#pragma unroll
    for (int i = 0; i < 8; i++)
        reinterpret_cast<unsigned*>(AswP)[tid + (i << 9)] = 0;
    __syncthreads();

    float pv[4][4];
#pragma unroll
    for (int nt = 0; nt < 4; nt++)
#pragma unroll
        for (int r = 0; r < 4; r++) pv[nt][r] = 0.0f;

    const int colb = wv * 64 + c0;           // + nt*16 at use
    const int aswz = (c0 & 7) << 4;          // A-panel XOR swizzle (row = c0)
    const int arp  = (c0 << 10) + (qf << 4); // row*1024 + qf*16
    const int bq   = (blk << 4) + (qf << 2); // batch row base
    // per-thread base into Wq fragment stream (kk stride = 8 KB)
    const char* wqb = reinterpret_cast<const char*>(Wq) + (wv * 64 + lane) * 16;

    for (int t = 0; t < TT; t++) {
        // K-loop: 16 kk x 4 MFMA. A from LDS panel; B: nt0/1 regs, nt2 LDS,
        // nt3 streamed from Wq with 3-deep rotating prefetch (static idx).
        float4v acc[4];
#pragma unroll
        for (int i = 0; i < 4; i++) acc[i] = (float4v){0.f, 0.f, 0.f, 0.f};
        uint4 sf[3];
        sf[0] = *reinterpret_cast<const uint4*>(wqb);
        sf[1] = *reinterpret_cast<const uint4*>(wqb + 8192);
#pragma unroll
        for (int kk = 0; kk < 16; kk++) {
            if (kk < 14)
                sf[(kk + 2) % 3] = *reinterpret_cast<const uint4*>(
                    wqb + (kk + 2) * 8192);
            const short8 a = *reinterpret_cast<const short8*>(
                AswP + ((arp + (kk << 6)) ^ aswz));
            const short8 b2 = *reinterpret_cast<const short8*>(&BswL[wv][kk][lane][0]);
            const uint4  s  = sf[kk % 3];
            const short8 b3 = __builtin_bit_cast(short8, s);
            acc[0] = __builtin_amdgcn_mfma_f32_16x16x32_bf16(a, bf[0][kk], acc[0], 0, 0, 0);
            acc[1] = __builtin_amdgcn_mfma_f32_16x16x32_bf16(a, bf[1][kk], acc[1], 0, 0, 0);
            acc[2] = __builtin_amdgcn_mfma_f32_16x16x32_bf16(a, b2,        acc[2], 0, 0, 0);
            acc[3] = __builtin_amdgcn_mfma_f32_16x16x32_bf16(a, b3,        acc[3], 0, 0, 0);
        }
        __syncthreads();                     // R: all A-panel reads done

        // operand loads (post-barrier; live only through the epilogue)
        const int pgb = ((t << 2) + blk) << 2;
        uint2 pe2[4], lk2[4], wr2[4];
#pragma unroll
        for (int r = 0; r < 4; r++) {
            const int off = ((pgb + r) << 11) + (tid << 2);
            pe2[r] = *reinterpret_cast<const uint2*>(&PeB[off]);
            lk2[r] = *reinterpret_cast<const uint2*>(&Pl2[off]);
            wr2[r] = *reinterpret_cast<const uint2*>(&Pw2[off]);
        }

        // epilogue: gates + tanh, update carry, dout store, A-panel for t+1
#pragma unroll
        for (int r = 0; r < 4; r++) {
#pragma unroll
            for (int nt = 0; nt < 4; nt++) {
                const unsigned pu = (nt < 2) ? pe2[r].x : pe2[r].y;
                const unsigned lu = (nt < 2) ? lk2[r].x : lk2[r].y;
                const unsigned wu = (nt < 2) ? wr2[r].x : wr2[r].y;
                const float pef = (nt & 1) ? bfhi(pu) : bflo(pu);
                const float lkf = (nt & 1) ? bfhi(lu) : bflo(lu);
                const float wrf = (nt & 1) ? bfhi(wu) : bflo(wu);
                const float pre  = acc[nt][r] + pef;          // pe incl. be+bp
                const float e    = __expf(2.0f * pre);
                const float cand = 1.0f - 2.0f / (e + 1.0f);  // tanh, inf-safe
                const float bel  = lkf * pv[nt][r] + wrf * cand;
                pv[nt][r] = bel;
                dout[((bq + r) << 18) + (t << 9) + colb + nt * 16] = bel;
                const int rl = (qf << 2) + r;
                const int wb = (((rl << 10) + ((colb + nt * 16) << 1))
                                ^ ((rl & 7) << 4));
                *reinterpret_cast<unsigned short*>(AswP + wb) = f2bf(bel);
            }
        }
        __syncthreads();                     // W: A-panel ready for t+1
    }
}

// ---------------------------------------------------------------------------
extern "C" void kernel_launch(void* const* d_in, const int* in_sizes, int n_in,
                              void* d_out, int out_size, void* d_ws, size_t ws_size,
                              hipStream_t stream) {
    (void)in_sizes; (void)n_in; (void)out_size; (void)ws_size;
    const float* X  = (const float*)d_in[0];
    const float* We = (const float*)d_in[1];
    const float* be = (const float*)d_in[2];
    const float* Wp = (const float*)d_in[3];
    const float* bp = (const float*)d_in[4];
    const float* Wl = (const float*)d_in[5];
    const float* bl = (const float*)d_in[6];
    const float* Ww = (const float*)d_in[7];
    const float* bw = (const float*)d_in[8];
    float* out = (float*)d_out;

    char* ws = (char*)d_ws;
    unsigned short* PeB = (unsigned short*)ws;                   // 32 MB
    unsigned short* Pl2 = (unsigned short*)(ws + 33554432);      // 32 MB
    unsigned short* Pw2 = (unsigned short*)(ws + 67108864);      // 32 MB
    unsigned short* Wq  = (unsigned short*)(ws + 100663296);     // 128 KB

    prep_kernel<<<dim3(128), 64, 0, stream>>>(Wp, Wq);
    proj_kernel<<<dim3(256, 3), 512, 0, stream>>>(X, We, be, bp, Wl, bl,
                                                  Ww, bw, PeB, Pl2, Pw2);
    rec_kernel<<<dim3(4), 512, 0, stream>>>(Wp, Wq, PeB, Pl2, Pw2, out);
}

// Round 9
// 2573.018 us; speedup vs baseline: 1.3990x; 1.2087x over previous
//
#include <hip/hip_runtime.h>
#include <math.h>

#define DD 512
#define TT 512

typedef __attribute__((ext_vector_type(8))) short short8;
typedef __attribute__((ext_vector_type(4))) float float4v;

static __device__ inline unsigned short f2bf(float f) {
    unsigned int b = __builtin_bit_cast(unsigned int, f);
    b += 0x7FFFu + ((b >> 16) & 1u);          // round-to-nearest-even
    return (unsigned short)(b >> 16);
}
static __device__ inline float bfhi(unsigned u) {   // high bf16 of a u32 pair
    return __builtin_bit_cast(float, u & 0xFFFF0000u);
}
static __device__ inline float bflo(unsigned u) {   // low bf16 of a u32 pair
    return __builtin_bit_cast(float, u << 16);
}

// ---------------------------------------------------------------------------
// Inline-asm MFMA with hazards closed STRUCTURALLY (R7 post-mortem):
//  * first MFMA of a chain: acc is the OUTPUT ("=&v", early-clobber — D never
//    aliases A/B/C); srcC = zc, a zero vector initialized once BEFORE the
//    t-loop and pinned by an opaque asm so it cannot be rematerialized as
//    v_movs adjacent to the MFMA (VALU-write->MFMA-srcC needs wait states
//    the compiler won't insert around opaque asm).
//  * last MFMA of a chain: carries its own MFMA->VALU-read cover (2x s_nop 7
//    INSIDE the asm), so any data-dependent read of acc lands after the nops.
//  * all volatile: relative order frozen.
//  srcB "a" = AGPR-direct (ISA §10: A,B from VGPR or AGPR) — removes the
//  per-step v_accvgpr shuttle storm (R3-R6: 128-reg fragment file parked in
//  AGPRs, active-CU VALUBusy ~34%).
// ---------------------------------------------------------------------------
static __device__ inline void mfma_first_a(float4v& d, short8 a, short8 b,
                                           float4v zc) {
    asm volatile("v_mfma_f32_16x16x32_bf16 %0, %1, %2, %3"
                 : "=&v"(d) : "v"(a), "a"(b), "v"(zc));
}
static __device__ inline void mfma_first_v(float4v& d, short8 a, short8 b,
                                           float4v zc) {
    asm volatile("v_mfma_f32_16x16x32_bf16 %0, %1, %2, %3"
                 : "=&v"(d) : "v"(a), "v"(b), "v"(zc));
}
static __device__ inline void mfma_acc_a(float4v& c, short8 a, short8 b) {
    asm volatile("v_mfma_f32_16x16x32_bf16 %0, %1, %2, %0"
                 : "+v"(c) : "v"(a), "a"(b));
}
static __device__ inline void mfma_acc_v(float4v& c, short8 a, short8 b) {
    asm volatile("v_mfma_f32_16x16x32_bf16 %0, %1, %2, %0"
                 : "+v"(c) : "v"(a), "v"(b));
}
static __device__ inline void mfma_last_a(float4v& c, short8 a, short8 b) {
    asm volatile("v_mfma_f32_16x16x32_bf16 %0, %1, %2, %0\n\t"
                 "s_nop 7\n\ts_nop 7"
                 : "+v"(c) : "v"(a), "a"(b));
}
static __device__ inline void mfma_last_v(float4v& c, short8 a, short8 b) {
    asm volatile("v_mfma_f32_16x16x32_bf16 %0, %1, %2, %0\n\t"
                 "s_nop 7\n\ts_nop 7"
                 : "+v"(c) : "v"(a), "v"(b));
}

// ---------------------------------------------------------------------------
// Kernel P: one-shot prep — repack Wp's nt=3 columns of each wave slice into
// MFMA-fragment order (identical to R6-verified version).
// ---------------------------------------------------------------------------
__global__ __launch_bounds__(64) void prep_kernel(
    const float* __restrict__ Wp, unsigned short* __restrict__ Wq)
{
    const int lane = threadIdx.x;      // 0..63
    const int g    = blockIdx.x;       // 0..127 = kk*8 + wv
    const int kk   = g >> 3;
    const int wv   = g & 7;
    const int col  = wv * 64 + 48 + (lane & 15);
    const int k0   = kk * 32 + (lane >> 4) * 8;
    unsigned short v[8];
#pragma unroll
    for (int j = 0; j < 8; j++) v[j] = f2bf(Wp[(k0 + j) * DD + col]);
    uint4 u;
    u.x = (unsigned)v[0] | ((unsigned)v[1] << 16);
    u.y = (unsigned)v[2] | ((unsigned)v[3] << 16);
    u.z = (unsigned)v[4] | ((unsigned)v[5] << 16);
    u.w = (unsigned)v[6] | ((unsigned)v[7] << 16);
    *reinterpret_cast<uint4*>(&Wq[(g * 64 + lane) * 8]) = u;
}

// ---------------------------------------------------------------------------
// Kernel A: fused projections — byte-identical to the R3/R4/R6-verified
// version.
//   PeB[page][tid*4+nt]  = bf16(X@We + be + bp)      page = ((t*4+b)*4+r)
//   Pl2[page][tid*4+nt]  = bf16(sigmoid(X@Wl + bl))
//   Pw2[page][tid*4+nt]  = bf16(sigmoid(X@Ww + bw))
// ---------------------------------------------------------------------------
__global__ __launch_bounds__(512) void proj_kernel(
    const float* __restrict__ X,
    const float* __restrict__ We, const float* __restrict__ be,
    const float* __restrict__ bp,
    const float* __restrict__ Wl, const float* __restrict__ bl,
    const float* __restrict__ Ww, const float* __restrict__ bw,
    unsigned short* __restrict__ PeB, unsigned short* __restrict__ Pl2,
    unsigned short* __restrict__ Pw2)
{
    __shared__ __align__(16) unsigned short Asw[8][64][8];
    __shared__ __align__(16) unsigned short Bsw[32][64][8];

    const int tid  = threadIdx.x;
    const int lane = tid & 63;
    const int wv   = tid >> 6;
    const int mat  = blockIdx.y;
    const int m0   = blockIdx.x * 128;

    const float* W = (mat == 0) ? We : (mat == 1 ? Wl : Ww);

    float4v acc[32];
#pragma unroll
    for (int i = 0; i < 32; i++) acc[i] = (float4v){0.f, 0.f, 0.f, 0.f};

    for (int kc = 0; kc < 16; kc++) {
        __syncthreads();
#pragma unroll
        for (int i = 0; i < 2; i++) {
            int f = tid + 512 * i;
            int m = f >> 3;
            int k = (f & 7) * 4;
            float4v xv = *reinterpret_cast<const float4v*>(
                &X[(m0 + m) * DD + kc * 32 + k]);
            int mt = m >> 4;
            int ln = (m & 15) | (((k >> 3) & 3) << 4);
            int j  = k & 7;
            Asw[mt][ln][j + 0] = f2bf(xv.x);
            Asw[mt][ln][j + 1] = f2bf(xv.y);
            Asw[mt][ln][j + 2] = f2bf(xv.z);
            Asw[mt][ln][j + 3] = f2bf(xv.w);
        }
#pragma unroll
        for (int i = 0; i < 8; i++) {
            int f = tid + 512 * i;
            int k = f >> 7;
            int n = (f & 127) * 4;
            float4v wv4 = *reinterpret_cast<const float4v*>(
                &W[(kc * 32 + k) * DD + n]);
            int q  = (k >> 3) & 3;
            int j  = k & 7;
            int nt = n >> 4;
            int lb = (n & 15) | (q << 4);
            Bsw[nt][lb + 0][j] = f2bf(wv4.x);
            Bsw[nt][lb + 1][j] = f2bf(wv4.y);
            Bsw[nt][lb + 2][j] = f2bf(wv4.z);
            Bsw[nt][lb + 3][j] = f2bf(wv4.w);
        }
        __syncthreads();
        short8 a = *reinterpret_cast<const short8*>(&Asw[wv][lane][0]);
#pragma unroll
        for (int nt = 0; nt < 32; nt++) {
            short8 b = *reinterpret_cast<const short8*>(&Bsw[nt][lane][0]);
            acc[nt] = __builtin_amdgcn_mfma_f32_16x16x32_bf16(a, b, acc[nt], 0, 0, 0);
        }
    }

    // ---- epilogue: operand-packed scatter ----
    const int q     = lane >> 4;
    const int c0    = lane & 15;
    const int tbase = m0 & 511;     // block covers one batch row, 128 t's
    const int rb    = m0 >> 9;      // batch row 0..63
    const int b     = rb >> 4;      // rec block
    const int qft   = (rb & 15) >> 2;
    const int rt    = rb & 3;

    unsigned short* P = (mat == 0) ? PeB : (mat == 1 ? Pl2 : Pw2);

#pragma unroll
    for (int wt = 0; wt < 8; wt++) {
        const int tidt = wt * 64 + qft * 16 + c0;
        float bs[4];
#pragma unroll
        for (int n2 = 0; n2 < 4; n2++) {
            const int col = (wt * 4 + n2) * 16 + c0;
            bs[n2] = (mat == 0) ? (be[col] + bp[col])
                                : ((mat == 1) ? bl[col] : bw[col]);
        }
#pragma unroll
        for (int r = 0; r < 4; r++) {
            const int t    = tbase + wv * 16 + q * 4 + r;
            const int page = (((t << 2) + b) << 2) + rt;
            float v[4];
#pragma unroll
            for (int n2 = 0; n2 < 4; n2++) {
                float x = acc[wt * 4 + n2][r] + bs[n2];
                v[n2] = (mat == 0) ? x : (1.0f / (1.0f + expf(-x)));
            }
            uint2 u;
            u.x = (unsigned)f2bf(v[0]) | ((unsigned)f2bf(v[1]) << 16);
            u.y = (unsigned)f2bf(v[2]) | ((unsigned)f2bf(v[3]) << 16);
            *reinterpret_cast<uint2*>(&P[(page << 11) + (tidt << 2)]) = u;
        }
    }
}

// ---------------------------------------------------------------------------
// Kernel B: persistent recurrence — R6 structure exactly (passed, 2675us),
// K-loop MFMAs in hazard-closed inline asm (see helper comments):
//   nt 0,1 B-fragments -> AGPR-direct ("a"), nt 2 -> LDS, nt 3 -> Wq stream.
// VGPR live set ~108 (acc 16 + zc 4 + sf 12 + operands 24 + pv 16 + addr)
// fits the 128 arch half; bf fills the 128 AGPR half exactly.
// ---------------------------------------------------------------------------
__global__ __attribute__((amdgpu_flat_work_group_size(512, 512),
                          amdgpu_waves_per_eu(2, 2)))
void rec_kernel(
    const float* __restrict__ Wp,
    const unsigned short* __restrict__ Wq,
    const unsigned short* __restrict__ PeB,
    const unsigned short* __restrict__ Pl2,
    const unsigned short* __restrict__ Pw2,
    float* __restrict__ dout)
{
    __shared__ __align__(16) unsigned short BswL[8][16][64][8]; // 128 KB
    __shared__ __align__(16) char AswP[16384];                  // 16 KB

    const int tid  = threadIdx.x;
    const int lane = tid & 63;
    const int wv   = tid >> 6;
    const int qf   = lane >> 4;
    const int c0   = lane & 15;
    const int blk  = blockIdx.x;     // 0..3

    short8 bf[2][16];                // B-fragments nt 0,1 -> AGPR class

    // ---- prologue: stage nt 0..2 through this wave's private LDS slice;
    // nt 0,1 -> registers (AGPR-parked), nt 2 stays resident in LDS.
#pragma unroll
    for (int nt = 0; nt < 3; nt++) {
        for (int it = 0; it < 32; it++) {
            const int f  = it * 64 + lane;
            const int k  = f >> 2;
            const int c4 = f & 3;
            const float4v w4 = *reinterpret_cast<const float4v*>(
                &Wp[(k << 9) + wv * 64 + nt * 16 + c4 * 4]);
            const int kk = k >> 5;
            const int qq = (k >> 3) & 3;
            const int j  = k & 7;
            const int lb = (c4 * 4) | (qq << 4);
            BswL[wv][kk][lb + 0][j] = f2bf(w4.x);
            BswL[wv][kk][lb + 1][j] = f2bf(w4.y);
            BswL[wv][kk][lb + 2][j] = f2bf(w4.z);
            BswL[wv][kk][lb + 3][j] = f2bf(w4.w);
        }
        if (nt < 2) {
#pragma unroll
            for (int kk = 0; kk < 16; kk++)
                bf[nt][kk] = *reinterpret_cast<const short8*>(&BswL[wv][kk][lane][0]);
        }
    }

    // belief(-1) = 0: zero the A-panel
#pragma unroll
    for (int i = 0; i < 8; i++)
        reinterpret_cast<unsigned*>(AswP)[tid + (i << 9)] = 0;
    __syncthreads();

    float pv[4][4];
#pragma unroll
    for (int nt = 0; nt < 4; nt++)
#pragma unroll
        for (int r = 0; r < 4; r++) pv[nt][r] = 0.0f;

    // zero srcC vector: initialized ONCE here (far from any MFMA read) and
    // pinned opaque so it cannot be rematerialized next to an MFMA.
    float4v zc = (float4v){0.f, 0.f, 0.f, 0.f};
    asm volatile("" : "+v"(zc));

    const int colb = wv * 64 + c0;           // + nt*16 at use
    const int aswz = (c0 & 7) << 4;          // A-panel XOR swizzle (row = c0)
    const int arp  = (c0 << 10) + (qf << 4); // row*1024 + qf*16
    const int bq   = (blk << 4) + (qf << 2); // batch row base
    // per-thread base into Wq fragment stream (kk stride = 8 KB)
    const char* wqb = reinterpret_cast<const char*>(Wq) + (wv * 64 + lane) * 16;

    for (int t = 0; t < TT; t++) {
        // K-loop: 16 kk x 4 MFMA. A from LDS panel; B: nt0/1 AGPR-direct,
        // nt2 LDS, nt3 streamed from Wq with 3-deep rotating prefetch.
        float4v acc[4];
        uint4 sf[3];
        sf[0] = *reinterpret_cast<const uint4*>(wqb);
        sf[1] = *reinterpret_cast<const uint4*>(wqb + 8192);
#pragma unroll
        for (int kk = 0; kk < 16; kk++) {
            if (kk < 14)
                sf[(kk + 2) % 3] = *reinterpret_cast<const uint4*>(
                    wqb + (kk + 2) * 8192);
            const short8 a = *reinterpret_cast<const short8*>(
                AswP + ((arp + (kk << 6)) ^ aswz));
            const short8 b2 = *reinterpret_cast<const short8*>(&BswL[wv][kk][lane][0]);
            const short8 b3 = __builtin_bit_cast(short8, sf[kk % 3]);
            if (kk == 0) {
                mfma_first_a(acc[0], a, bf[0][0], zc);
                mfma_first_a(acc[1], a, bf[1][0], zc);
                mfma_first_v(acc[2], a, b2, zc);
                mfma_first_v(acc[3], a, b3, zc);
            } else if (kk == 15) {
                mfma_last_a(acc[0], a, bf[0][15]);
                mfma_last_a(acc[1], a, bf[1][15]);
                mfma_last_v(acc[2], a, b2);
                mfma_last_v(acc[3], a, b3);
            } else {
                mfma_acc_a(acc[0], a, bf[0][kk]);
                mfma_acc_a(acc[1], a, bf[1][kk]);
                mfma_acc_v(acc[2], a, b2);
                mfma_acc_v(acc[3], a, b3);
            }
        }
        __syncthreads();                     // R: all A-panel reads done

        // operand loads (post-barrier; live only through the epilogue)
        const int pgb = ((t << 2) + blk) << 2;
        uint2 pe2[4], lk2[4], wr2[4];
#pragma unroll
        for (int r = 0; r < 4; r++) {
            const int off = ((pgb + r) << 11) + (tid << 2);
            pe2[r] = *reinterpret_cast<const uint2*>(&PeB[off]);
            lk2[r] = *reinterpret_cast<const uint2*>(&Pl2[off]);
            wr2[r] = *reinterpret_cast<const uint2*>(&Pw2[off]);
        }

        // epilogue: gates + tanh, update carry, dout store, A-panel for t+1
#pragma unroll
        for (int r = 0; r < 4; r++) {
#pragma unroll
            for (int nt = 0; nt < 4; nt++) {
                const unsigned pu = (nt < 2) ? pe2[r].x : pe2[r].y;
                const unsigned lu = (nt < 2) ? lk2[r].x : lk2[r].y;
                const unsigned wu = (nt < 2) ? wr2[r].x : wr2[r].y;
                const float pef = (nt & 1) ? bfhi(pu) : bflo(pu);
                const float lkf = (nt & 1) ? bfhi(lu) : bflo(lu);
                const float wrf = (nt & 1) ? bfhi(wu) : bflo(wu);
                const float pre  = acc[nt][r] + pef;          // pe incl. be+bp
                const float e    = __expf(2.0f * pre);
                const float cand = 1.0f - 2.0f / (e + 1.0f);  // tanh, inf-safe
                const float bel  = lkf * pv[nt][r] + wrf * cand;
                pv[nt][r] = bel;
                dout[((bq + r) << 18) + (t << 9) + colb + nt * 16] = bel;
                const int rl = (qf << 2) + r;
                const int wb = (((rl << 10) + ((colb + nt * 16) << 1))
                                ^ ((rl & 7) << 4));
                *reinterpret_cast<unsigned short*>(AswP + wb) = f2bf(bel);
            }
        }
        __syncthreads();                     // W: A-panel ready for t+1
    }
}

// ---------------------------------------------------------------------------
extern "C" void kernel_launch(void* const* d_in, const int* in_sizes, int n_in,
                              void* d_out, int out_size, void* d_ws, size_t ws_size,
                              hipStream_t stream) {
    (void)in_sizes; (void)n_in; (void)out_size; (void)ws_size;
    const float* X  = (const float*)d_in[0];
    const float* We = (const float*)d_in[1];
    const float* be = (const float*)d_in[2];
    const float* Wp = (const float*)d_in[3];
    const float* bp = (const float*)d_in[4];
    const float* Wl = (const float*)d_in[5];
    const float* bl = (const float*)d_in[6];
    const float* Ww = (const float*)d_in[7];
    const float* bw = (const float*)d_in[8];
    float* out = (float*)d_out;

    char* ws = (char*)d_ws;
    unsigned short* PeB = (unsigned short*)ws;                   // 32 MB
    unsigned short* Pl2 = (unsigned short*)(ws + 33554432);      // 32 MB
    unsigned short* Pw2 = (unsigned short*)(ws + 67108864);      // 32 MB
    unsigned short* Wq  = (unsigned short*)(ws + 100663296);     // 128 KB

    prep_kernel<<<dim3(128), 64, 0, stream>>>(Wp, Wq);
    proj_kernel<<<dim3(256, 3), 512, 0, stream>>>(X, We, be, bp, Wl, bl,
                                                  Ww, bw, PeB, Pl2, Pw2);
    rec_kernel<<<dim3(4), 512, 0, stream>>>(Wp, Wq, PeB, Pl2, Pw2, out);
}